// Round 7
// baseline (288.783 us; speedup 1.0000x reference)
//
#include <hip/hip_runtime.h>
#include <hip/hip_bf16.h>
#include <math.h>

#define NEG_SLOPE 0.2f
// wave-internal LDS ordering: each wave owns a private LDS slice, so a plain
// lgkmcnt drain orders its own ds ops; no __syncthreads (degrees diverge).
#define LDS_FENCE() asm volatile("s_waitcnt lgkmcnt(0)" ::: "memory")

// ---------- CSR build over dst ----------
__global__ void k_count(const int* __restrict__ ei, int E, int N, int* __restrict__ counts) {
    int e = blockIdx.x * blockDim.x + threadIdx.x;
    int Etot = E + N;
    if (e >= Etot) return;
    int d = (e < E) ? ei[E + e] : (e - E);
    atomicAdd(&counts[d], 1);
}

// single-pass scan: 1024 threads x 16 elems/thread (N <= 16384), one barrier set
__global__ __launch_bounds__(1024) void k_scan(const int* __restrict__ counts,
                                               int* __restrict__ rowptr, int N) {
    __shared__ int wsums[16];
    __shared__ int wpref[17];
    int t = threadIdx.x;
    int lane = t & 63, wave = t >> 6;
    int i0 = t * 16;
    int loc[16];
    int sum = 0;
#pragma unroll
    for (int j = 0; j < 16; ++j) {
        int i = i0 + j;
        int v = (i < N) ? counts[i] : 0;
        loc[j] = sum;
        sum += v;
    }
    int x = sum;
#pragma unroll
    for (int off = 1; off < 64; off <<= 1) {
        int tv = __shfl_up(x, off);
        if (lane >= off) x += tv;
    }
    if (lane == 63) wsums[wave] = x;
    __syncthreads();
    if (t == 0) {
        int a = 0;
#pragma unroll
        for (int w = 0; w < 16; ++w) { wpref[w] = a; a += wsums[w]; }
        wpref[16] = a;
    }
    __syncthreads();
    int excl = wpref[wave] + x - sum;
#pragma unroll
    for (int j = 0; j < 16; ++j) {
        int i = i0 + j;
        if (i < N) rowptr[i] = excl + loc[j];
    }
    if (t == 0) rowptr[N] = wpref[16];
}

// fill via decrementing counts as cursor: pos = rowptr[d] + (--counts[d])
__global__ void k_fill_csr(const int* __restrict__ ei, int E, int N,
                           const int* __restrict__ rowptr, int* __restrict__ counts,
                           int* __restrict__ col) {
    int e = blockIdx.x * blockDim.x + threadIdx.x;
    int Etot = E + N;
    if (e >= Etot) return;
    int s, d;
    if (e < E) { s = ei[e]; d = ei[E + e]; } else { s = d = e - E; }
    int pos = rowptr[d] + atomicSub(&counts[d], 1) - 1;
    col[pos] = s;
}

// ---------- GEMM: C[n,j] = sum_k X[n,k]*W[k,j], 256 cols total ----------
// grid (ceil(N/32), 2): tile 32 rows x 128 cols (col half), 256 thr = 4 waves.
// W read direct from global (L2-resident). Invariant (r4/r5): W L2 traffic =
// 2N/rowsPerThread x 128KB -> rPT=8 gives 320MB ~ 9us. X staged in LDS,
// compute reads are wave-uniform b128 broadcasts. No inner barrier (single
// stage), 626 blocks ~ 9.8 waves/CU hide the W-load latency.
template <int K>
__global__ __launch_bounds__(256) void k_gemm_cs(const float* __restrict__ X,
                                                 const float* __restrict__ W,
                                                 float* __restrict__ C, int N) {
    __shared__ float xs[32][K];
    int t = threadIdx.x;
    int n0 = blockIdx.x * 32;
    int ch = blockIdx.y;
    for (int idx = t; idx < 32 * (K / 4); idx += 256) {
        int r = idx / (K / 4), kq = idx - r * (K / 4);
        int n = n0 + r;
        float4 v = {0.f, 0.f, 0.f, 0.f};
        if (n < N) v = ((const float4*)(X + (size_t)n * K))[kq];
        *(float4*)&xs[r][kq * 4] = v;
    }
    __syncthreads();
    int lane = t & 63, wave = t >> 6;
    int r0 = wave * 8;
    const float* Wp = W + ch * 128 + lane * 2;
    float2 acc[8] = {};
#pragma unroll 2
    for (int k = 0; k < K; k += 4) {
        float2 w0 = *(const float2*)(Wp + (size_t)k * 256);
        float2 w1 = *(const float2*)(Wp + (size_t)(k + 1) * 256);
        float2 w2 = *(const float2*)(Wp + (size_t)(k + 2) * 256);
        float2 w3 = *(const float2*)(Wp + (size_t)(k + 3) * 256);
#pragma unroll
        for (int rr = 0; rr < 8; ++rr) {
            float4 xv = *(const float4*)&xs[r0 + rr][k];
            acc[rr].x = fmaf(xv.x, w0.x, acc[rr].x);
            acc[rr].y = fmaf(xv.x, w0.y, acc[rr].y);
            acc[rr].x = fmaf(xv.y, w1.x, acc[rr].x);
            acc[rr].y = fmaf(xv.y, w1.y, acc[rr].y);
            acc[rr].x = fmaf(xv.z, w2.x, acc[rr].x);
            acc[rr].y = fmaf(xv.z, w2.y, acc[rr].y);
            acc[rr].x = fmaf(xv.w, w3.x, acc[rr].x);
            acc[rr].y = fmaf(xv.w, w3.y, acc[rr].y);
        }
    }
#pragma unroll
    for (int rr = 0; rr < 8; ++rr) {
        int n = n0 + r0 + rr;
        if (n < N) *(float2*)(C + (size_t)n * 256 + ch * 128 + lane * 2) = acc[rr];
    }
}

// ---------- layer-1 attention logits: thread per (n,h), ch=16 ----------
__global__ void k_logits1(const float* __restrict__ H, const float* __restrict__ a_src,
                          const float* __restrict__ a_dst, float* __restrict__ als,
                          float* __restrict__ ald, int NH) {
    int i = blockIdx.x * blockDim.x + threadIdx.x;
    if (i >= NH) return;
    int h = i & 15;
    const float4* hp = (const float4*)(H + (size_t)i * 16);
    const float4* as = (const float4*)(a_src + h * 16);
    const float4* ad = (const float4*)(a_dst + h * 16);
    float s = 0.f, d = 0.f;
#pragma unroll
    for (int q = 0; q < 4; ++q) {
        float4 hv = hp[q], sv = as[q], dv = ad[q];
        s += hv.x * sv.x + hv.y * sv.y + hv.z * sv.z + hv.w * sv.w;
        d += hv.x * dv.x + hv.y * dv.y + hv.z * dv.z + hv.w * dv.w;
    }
    als[i] = s;
    ald[i] = d;
}

// ---------- layer-2 attention logits: wave per node, D=256 ----------
__global__ __launch_bounds__(256) void k_logits2(const float* __restrict__ H,
                                                 const float* __restrict__ a_src,
                                                 const float* __restrict__ a_dst,
                                                 float* __restrict__ als,
                                                 float* __restrict__ ald, int N) {
    int wave = threadIdx.x >> 6, lane = threadIdx.x & 63;
    int n = blockIdx.x * 4 + wave;
    if (n >= N) return;
    float4 hv = *(const float4*)(H + (size_t)n * 256 + lane * 4);
    float4 sv = *(const float4*)(a_src + lane * 4);
    float4 dv = *(const float4*)(a_dst + lane * 4);
    float s = hv.x * sv.x + hv.y * sv.y + hv.z * sv.z + hv.w * sv.w;
    float d = hv.x * dv.x + hv.y * dv.y + hv.z * dv.z + hv.w * dv.w;
#pragma unroll
    for (int off = 32; off >= 1; off >>= 1) {
        s += __shfl_xor(s, off);
        d += __shfl_xor(d, off);
    }
    if (lane == 0) { als[n] = s; ald[n] = d; }
}

// ---------- fused GAT gather, 1 head, channel-half split ----------
__global__ __launch_bounds__(256) void k_gather_h1(
    const int* __restrict__ rowptr, const int* __restrict__ col,
    const float* __restrict__ H, const float* __restrict__ als,
    const float* __restrict__ ald, const float* __restrict__ bias,
    float* __restrict__ out, int N) {
    __shared__ float2 sw[4][64];
    int wave = threadIdx.x >> 6, lane = threadIdx.x & 63;
    int n = blockIdx.x * 4 + wave;
    if (n >= N) return;
    int hf = blockIdx.y;
    int coff = hf * 128 + lane * 2;
    int start = rowptr[n], end = rowptr[n + 1];
    float aldv = ald[n];
    float2 acc = {0.f, 0.f};
    float swsum = 0.f;
    const float* Hh = H + coff;
    for (int base = start; base < end; base += 64) {
        int len = min(64, end - base);
        int s = 0;
        float w = 0.f;
        if (lane < len) {
            s = col[base + lane];
            float v = als[s] + aldv;
            v = v >= 0.f ? v : NEG_SLOPE * v;
            w = __expf(v);
        }
        swsum += w;
        sw[wave][lane] = make_float2(__int_as_float(s), w);
        LDS_FENCE();
#pragma unroll 4
        for (int e = 0; e < len; ++e) {
            float2 p = sw[wave][e];
            int se = __float_as_int(p.x);
            float we = p.y;
            float2 hv = *(const float2*)(Hh + (size_t)se * 256);
            acc.x = fmaf(we, hv.x, acc.x);
            acc.y = fmaf(we, hv.y, acc.y);
        }
        LDS_FENCE();
    }
#pragma unroll
    for (int off = 32; off >= 1; off >>= 1) swsum += __shfl_xor(swsum, off);
    float inv = 1.0f / swsum;
    float2 b2v = *(const float2*)(bias + coff);
    float2 r;
    r.x = fmaf(acc.x, inv, b2v.x);
    r.y = fmaf(acc.y, inv, b2v.y);
    *(float2*)(out + (size_t)n * 256 + coff) = r;
}

// ---------- fused GAT gather, 16 heads x 16ch, channel-half split ----------
__global__ __launch_bounds__(256) void k_gather_h16(
    const int* __restrict__ rowptr, const int* __restrict__ col,
    const float* __restrict__ H, const float* __restrict__ als,
    const float* __restrict__ ald, const float* __restrict__ bias,
    float* __restrict__ out, int N) {
    __shared__ int s_lds[4][32];
    __shared__ float w_lds[4][32 * 8];
    int wave = threadIdx.x >> 6, lane = threadIdx.x & 63;
    int n = blockIdx.x * 4 + wave;
    if (n >= N) return;
    int hf = blockIdx.y;
    int coff = hf * 128 + lane * 2;
    int start = rowptr[n], end = rowptr[n + 1];
    int hW = (hf << 3) + (lane & 7);   // head this lane computes logits for
    int eW = lane >> 3;                // edge sub-slot 0..7
    float aldW = ald[n * 16 + hW];
    float2 acc = {0.f, 0.f};
    float swp = 0.f;                   // partial w-sum for head hW
    const float* Hh = H + coff;
    for (int base = start; base < end; base += 32) {
        int len = min(32, end - base);
        if (lane < 32) s_lds[wave][lane] = (lane < len) ? col[base + lane] : 0;
        LDS_FENCE();
#pragma unroll
        for (int k = 0; k < 4; ++k) {
            int esub = (k << 3) + eW;
            float w = 0.f;
            if (esub < len) {
                int s = s_lds[wave][esub];
                float v = als[s * 16 + hW] + aldW;
                v = v >= 0.f ? v : NEG_SLOPE * v;
                w = __expf(v);
            }
            w_lds[wave][(esub << 3) + (lane & 7)] = w;  // = k*64+lane: linear
            swp += w;
        }
        LDS_FENCE();
#pragma unroll 4
        for (int e = 0; e < len; ++e) {
            int se = s_lds[wave][e];
            float we = w_lds[wave][(e << 3) + (lane >> 3)];  // broadcast per 8 lanes
            float2 hv = *(const float2*)(Hh + (size_t)se * 256);
            acc.x = fmaf(we, hv.x, acc.x);
            acc.y = fmaf(we, hv.y, acc.y);
        }
        LDS_FENCE();
    }
    swp += __shfl_xor(swp, 8);
    swp += __shfl_xor(swp, 16);
    swp += __shfl_xor(swp, 32);
    float inv = 1.0f / __shfl(swp, lane >> 3);
    float2 b2v = *(const float2*)(bias + coff);
    float2 r;
    r.x = fmaxf(fmaf(acc.x, inv, b2v.x), 0.f);
    r.y = fmaxf(fmaf(acc.y, inv, b2v.y), 0.f);
    *(float2*)(out + (size_t)n * 256 + coff) = r;
}

// ---------- fused mean-pool + final linear: one block per graph ----------
__device__ __forceinline__ int lower_bound_i(const int* __restrict__ a, int n, int v) {
    int lo = 0, hi = n;
    while (lo < hi) {
        int mid = (lo + hi) >> 1;
        if (a[mid] < v) lo = mid + 1; else hi = mid;
    }
    return lo;
}

__global__ __launch_bounds__(1024) void k_pool_final(const float* __restrict__ B,
                                                     const int* __restrict__ batch,
                                                     const float* __restrict__ lw,
                                                     const float* __restrict__ lb,
                                                     float* __restrict__ out,
                                                     int N, int L) {
    __shared__ float psum[4][256];
    __shared__ float csum[256];
    int t = threadIdx.x;
    int c = t & 255, q = t >> 8;
    int g = blockIdx.x;
    int lo = lower_bound_i(batch, N, g);
    int hi = lower_bound_i(batch, N, g + 1);
    int len = hi - lo;
    int per = (len + 3) >> 2;
    int s0 = lo + q * per, s1 = min(hi, s0 + per);
    float acc = 0.f;
    for (int r = s0; r < s1; ++r) acc += B[(size_t)r * 256 + c];
    psum[q][c] = acc;
    __syncthreads();
    if (t < 256) csum[t] = psum[0][t] + psum[1][t] + psum[2][t] + psum[3][t];
    __syncthreads();
    int wave = t >> 6, lane = t & 63;
    if (wave < L) {
        int l = wave;
        float a = csum[lane] * lw[lane * L + l] +
                  csum[lane + 64] * lw[(lane + 64) * L + l] +
                  csum[lane + 128] * lw[(lane + 128) * L + l] +
                  csum[lane + 192] * lw[(lane + 192) * L + l];
#pragma unroll
        for (int off = 32; off >= 1; off >>= 1) a += __shfl_xor(a, off);
        if (lane == 0) out[g * L + l] = a / fmaxf((float)len, 1.0f) + lb[l];
    }
}

extern "C" void kernel_launch(void* const* d_in, const int* in_sizes, int n_in,
                              void* d_out, int out_size, void* d_ws, size_t ws_size,
                              hipStream_t stream) {
    const float* x   = (const float*)d_in[0];
    const int*   ei  = (const int*)d_in[1];
    const int*   bat = (const int*)d_in[2];
    const float* W1  = (const float*)d_in[3];
    const float* as1 = (const float*)d_in[4];
    const float* ad1 = (const float*)d_in[5];
    const float* b1  = (const float*)d_in[6];
    const float* W2  = (const float*)d_in[7];
    const float* as2 = (const float*)d_in[8];
    const float* ad2 = (const float*)d_in[9];
    const float* b2  = (const float*)d_in[10];
    const float* lw  = (const float*)d_in[11];
    const float* lb  = (const float*)d_in[12];
    float* out = (float*)d_out;

    const int N = in_sizes[2];        // 10000
    const int E = in_sizes[1] / 2;    // 320000
    const int G = 64, L = 10;
    const int Etot = E + N;

    // workspace layout (floats)
    float* A    = (float*)d_ws;              // [N,256] h1 then h2
    float* B    = A + (size_t)N * 256;       // [N,256] out1 then out2
    float* als1 = B + (size_t)N * 256;       // [N,16]
    float* ald1 = als1 + (size_t)N * 16;
    float* als2 = ald1 + (size_t)N * 16;     // [N]
    float* ald2 = als2 + N;
    int* counts = (int*)(ald2 + N);          // [N]
    int* rowptr = counts + N;                // [N+1]
    int* col    = rowptr + N + 1;            // [Etot]

    const int BS = 256;
    auto nb = [](int n, int b) { return (n + b - 1) / b; };
    int nodes4 = nb(N, 4);
    int rows32 = nb(N, 32);

    // ---- CSR build (dst-indexed) ----
    hipMemsetAsync(counts, 0, (size_t)N * 4, stream);
    k_count<<<nb(Etot, BS), BS, 0, stream>>>(ei, E, N, counts);
    k_scan<<<1, 1024, 0, stream>>>(counts, rowptr, N);
    k_fill_csr<<<nb(Etot, BS), BS, 0, stream>>>(ei, E, N, rowptr, counts, col);

    // ---- layer 1 ----
    k_gemm_cs<128><<<dim3(rows32, 2), BS, 0, stream>>>(x, W1, A, N);
    k_logits1<<<nb(N * 16, BS), BS, 0, stream>>>(A, as1, ad1, als1, ald1, N * 16);
    k_gather_h16<<<dim3(nodes4, 2), BS, 0, stream>>>(rowptr, col, A, als1, ald1, b1, B, N);

    // ---- layer 2 ----
    k_gemm_cs<256><<<dim3(rows32, 2), BS, 0, stream>>>(B, W2, A, N);
    k_logits2<<<nodes4, BS, 0, stream>>>(A, as2, ad2, als2, ald2, N);
    k_gather_h1<<<dim3(nodes4, 2), BS, 0, stream>>>(rowptr, col, A, als2, ald2, b2, B, N);

    // ---- fused pool + final linear ----
    k_pool_final<<<G, 1024, 0, stream>>>(B, bat, lw, lb, out, N, L);
}

// Round 8
// 249.296 us; speedup vs baseline: 1.1584x; 1.1584x over previous
//
#include <hip/hip_runtime.h>
#include <hip/hip_bf16.h>
#include <math.h>

#define NEG_SLOPE 0.2f
// wave-internal LDS ordering: each wave owns a private LDS slice, so a plain
// lgkmcnt drain orders its own ds ops; no __syncthreads (degrees diverge).
#define LDS_FENCE() asm volatile("s_waitcnt lgkmcnt(0)" ::: "memory")

// ===================== partition-sort CSR build (dst-indexed) =====================
// Partitions of 32 dst values; NP = ceil(N/32) <= 384; NB = 128 scatter blocks.
// No global returning atomics (r7's k_fill_csr: 43.6us, 17MB of partial-line
// RMW from 4B random scatter + per-address serialization of returning atomicSub).
#define CSR_NB 128

// pass A: per-block histogram over partitions
__global__ __launch_bounds__(256) void k_parthist(const int* __restrict__ ei, int E, int N,
                                                  int NP, int CE, int* __restrict__ hist) {
    __shared__ int lhist[384];
    int t = threadIdx.x, b = blockIdx.x;
    for (int p = t; p < 384; p += 256) lhist[p] = 0;
    __syncthreads();
    int Etot = E + N;
    int e0 = b * CE, e1 = min(Etot, e0 + CE);
    for (int e = e0 + t; e < e1; e += 256) {
        int d = (e < E) ? ei[E + e] : (e - E);
        atomicAdd(&lhist[d >> 5], 1);
    }
    __syncthreads();
    for (int p = t; p < NP; p += 256) hist[b * NP + p] = lhist[p];
}

// pass S: partition totals -> exclusive scan -> per-(block,partition) offsets
__global__ __launch_bounds__(512) void k_partscan(int* __restrict__ hist, int NP,
                                                  int* __restrict__ partBase,
                                                  int* __restrict__ rowptr, int N) {
    __shared__ int wsums[8];
    int t = threadIdx.x, lane = t & 63, wave = t >> 6;
    int tot = 0;
    if (t < NP)
        for (int b = 0; b < CSR_NB; ++b) tot += hist[b * NP + t];
    int x = tot;
#pragma unroll
    for (int off = 1; off < 64; off <<= 1) {
        int v = __shfl_up(x, off);
        if (lane >= off) x += v;
    }
    if (lane == 63) wsums[wave] = x;
    __syncthreads();
    int wp = 0;
    for (int w = 0; w < 8; ++w) {
        int s = wsums[w];
        if (w < wave) wp += s;
    }
    int excl = wp + x - tot;
    if (t < NP) {
        partBase[t] = excl;
        int run = excl;
        for (int b = 0; b < CSR_NB; ++b) {
            int h = hist[b * NP + t];
            hist[b * NP + t] = run;
            run += h;
        }
        if (t == NP - 1) {
            partBase[NP] = run;
            rowptr[N] = run;     // = Etot
        }
    }
}

// pass B: scatter packed (src<<5 | dst&31) into partition segments
__global__ __launch_bounds__(256) void k_partscatter(const int* __restrict__ ei, int E, int N,
                                                     int NP, int CE,
                                                     const int* __restrict__ hist,
                                                     int* __restrict__ tmp) {
    __shared__ int cursor[384];
    int t = threadIdx.x, b = blockIdx.x;
    for (int p = t; p < NP; p += 256) cursor[p] = hist[b * NP + p];
    __syncthreads();
    int Etot = E + N;
    int e0 = b * CE, e1 = min(Etot, e0 + CE);
    for (int e = e0 + t; e < e1; e += 256) {
        int s, d;
        if (e < E) { s = ei[e]; d = ei[E + e]; } else { s = d = e - E; }
        int pos = atomicAdd(&cursor[d >> 5], 1);   // LDS atomic: fast
        tmp[pos] = (s << 5) | (d & 31);
    }
}

// pass C: one block per partition -> rowptr (dense) + col (dense)
__global__ __launch_bounds__(256) void k_csr_final(const int* __restrict__ tmp,
                                                   const int* __restrict__ partBase,
                                                   int* __restrict__ rowptr,
                                                   int* __restrict__ col, int N) {
    __shared__ int dcnt[32], dcur[32];
    int t = threadIdx.x, p = blockIdx.x;
    int base = partBase[p], end = partBase[p + 1];
    if (t < 32) dcnt[t] = 0;
    __syncthreads();
    for (int i = base + t; i < end; i += 256) atomicAdd(&dcnt[tmp[i] & 31], 1);
    __syncthreads();
    if (t < 32) {
        int v = dcnt[t];
        int x = v;
#pragma unroll
        for (int off = 1; off < 32; off <<= 1) {
            int u = __shfl_up(x, off);
            if (t >= off) x += u;
        }
        int excl = x - v;
        dcur[t] = excl;
        int dst = (p << 5) + t;
        if (dst < N) rowptr[dst] = base + excl;
    }
    __syncthreads();
    for (int i = base + t; i < end; i += 256) {
        int v = tmp[i];
        int pos = atomicAdd(&dcur[v & 31], 1);
        col[base + pos] = v >> 5;
    }
}

// ---------- GEMM: C[n,j] = sum_k X[n,k]*W[k,j], 256 cols total ----------
// grid (ceil(N/32), 2): tile 32 rows x 128 cols (col half), 256 thr = 4 waves.
// All 4 waves read identical W addresses (rows differ via LDS xs) -> W served
// from L1/L2; X staged in LDS, compute reads are wave-uniform b128 broadcasts.
template <int K>
__global__ __launch_bounds__(256) void k_gemm_cs(const float* __restrict__ X,
                                                 const float* __restrict__ W,
                                                 float* __restrict__ C, int N) {
    __shared__ float xs[32][K];
    int t = threadIdx.x;
    int n0 = blockIdx.x * 32;
    int ch = blockIdx.y;
    for (int idx = t; idx < 32 * (K / 4); idx += 256) {
        int r = idx / (K / 4), kq = idx - r * (K / 4);
        int n = n0 + r;
        float4 v = {0.f, 0.f, 0.f, 0.f};
        if (n < N) v = ((const float4*)(X + (size_t)n * K))[kq];
        *(float4*)&xs[r][kq * 4] = v;
    }
    __syncthreads();
    int lane = t & 63, wave = t >> 6;
    int r0 = wave * 8;
    const float* Wp = W + ch * 128 + lane * 2;
    float2 acc[8] = {};
#pragma unroll 2
    for (int k = 0; k < K; k += 4) {
        float2 w0 = *(const float2*)(Wp + (size_t)k * 256);
        float2 w1 = *(const float2*)(Wp + (size_t)(k + 1) * 256);
        float2 w2 = *(const float2*)(Wp + (size_t)(k + 2) * 256);
        float2 w3 = *(const float2*)(Wp + (size_t)(k + 3) * 256);
#pragma unroll
        for (int rr = 0; rr < 8; ++rr) {
            float4 xv = *(const float4*)&xs[r0 + rr][k];
            acc[rr].x = fmaf(xv.x, w0.x, acc[rr].x);
            acc[rr].y = fmaf(xv.x, w0.y, acc[rr].y);
            acc[rr].x = fmaf(xv.y, w1.x, acc[rr].x);
            acc[rr].y = fmaf(xv.y, w1.y, acc[rr].y);
            acc[rr].x = fmaf(xv.z, w2.x, acc[rr].x);
            acc[rr].y = fmaf(xv.z, w2.y, acc[rr].y);
            acc[rr].x = fmaf(xv.w, w3.x, acc[rr].x);
            acc[rr].y = fmaf(xv.w, w3.y, acc[rr].y);
        }
    }
#pragma unroll
    for (int rr = 0; rr < 8; ++rr) {
        int n = n0 + r0 + rr;
        if (n < N) *(float2*)(C + (size_t)n * 256 + ch * 128 + lane * 2) = acc[rr];
    }
}

// ---------- layer-1 attention logits: thread per (n,h), ch=16 ----------
__global__ void k_logits1(const float* __restrict__ H, const float* __restrict__ a_src,
                          const float* __restrict__ a_dst, float* __restrict__ als,
                          float* __restrict__ ald, int NH) {
    int i = blockIdx.x * blockDim.x + threadIdx.x;
    if (i >= NH) return;
    int h = i & 15;
    const float4* hp = (const float4*)(H + (size_t)i * 16);
    const float4* as = (const float4*)(a_src + h * 16);
    const float4* ad = (const float4*)(a_dst + h * 16);
    float s = 0.f, d = 0.f;
#pragma unroll
    for (int q = 0; q < 4; ++q) {
        float4 hv = hp[q], sv = as[q], dv = ad[q];
        s += hv.x * sv.x + hv.y * sv.y + hv.z * sv.z + hv.w * sv.w;
        d += hv.x * dv.x + hv.y * dv.y + hv.z * dv.z + hv.w * dv.w;
    }
    als[i] = s;
    ald[i] = d;
}

// ---------- layer-2 attention logits: wave per node, D=256 ----------
__global__ __launch_bounds__(256) void k_logits2(const float* __restrict__ H,
                                                 const float* __restrict__ a_src,
                                                 const float* __restrict__ a_dst,
                                                 float* __restrict__ als,
                                                 float* __restrict__ ald, int N) {
    int wave = threadIdx.x >> 6, lane = threadIdx.x & 63;
    int n = blockIdx.x * 4 + wave;
    if (n >= N) return;
    float4 hv = *(const float4*)(H + (size_t)n * 256 + lane * 4);
    float4 sv = *(const float4*)(a_src + lane * 4);
    float4 dv = *(const float4*)(a_dst + lane * 4);
    float s = hv.x * sv.x + hv.y * sv.y + hv.z * sv.z + hv.w * sv.w;
    float d = hv.x * dv.x + hv.y * dv.y + hv.z * dv.z + hv.w * dv.w;
#pragma unroll
    for (int off = 32; off >= 1; off >>= 1) {
        s += __shfl_xor(s, off);
        d += __shfl_xor(d, off);
    }
    if (lane == 0) { als[n] = s; ald[n] = d; }
}

// ---------- fused GAT gather, 1 head, channel-half split ----------
__global__ __launch_bounds__(256) void k_gather_h1(
    const int* __restrict__ rowptr, const int* __restrict__ col,
    const float* __restrict__ H, const float* __restrict__ als,
    const float* __restrict__ ald, const float* __restrict__ bias,
    float* __restrict__ out, int N) {
    __shared__ float2 sw[4][64];
    int wave = threadIdx.x >> 6, lane = threadIdx.x & 63;
    int n = blockIdx.x * 4 + wave;
    if (n >= N) return;
    int hf = blockIdx.y;
    int coff = hf * 128 + lane * 2;
    int start = rowptr[n], end = rowptr[n + 1];
    float aldv = ald[n];
    float2 acc = {0.f, 0.f};
    float swsum = 0.f;
    const float* Hh = H + coff;
    for (int base = start; base < end; base += 64) {
        int len = min(64, end - base);
        int s = 0;
        float w = 0.f;
        if (lane < len) {
            s = col[base + lane];
            float v = als[s] + aldv;
            v = v >= 0.f ? v : NEG_SLOPE * v;
            w = __expf(v);
        }
        swsum += w;
        sw[wave][lane] = make_float2(__int_as_float(s), w);
        LDS_FENCE();
#pragma unroll 4
        for (int e = 0; e < len; ++e) {
            float2 p = sw[wave][e];
            int se = __float_as_int(p.x);
            float we = p.y;
            float2 hv = *(const float2*)(Hh + (size_t)se * 256);
            acc.x = fmaf(we, hv.x, acc.x);
            acc.y = fmaf(we, hv.y, acc.y);
        }
        LDS_FENCE();
    }
#pragma unroll
    for (int off = 32; off >= 1; off >>= 1) swsum += __shfl_xor(swsum, off);
    float inv = 1.0f / swsum;
    float2 b2v = *(const float2*)(bias + coff);
    float2 r;
    r.x = fmaf(acc.x, inv, b2v.x);
    r.y = fmaf(acc.y, inv, b2v.y);
    *(float2*)(out + (size_t)n * 256 + coff) = r;
}

// ---------- fused GAT gather, 16 heads x 16ch, channel-half split ----------
__global__ __launch_bounds__(256) void k_gather_h16(
    const int* __restrict__ rowptr, const int* __restrict__ col,
    const float* __restrict__ H, const float* __restrict__ als,
    const float* __restrict__ ald, const float* __restrict__ bias,
    float* __restrict__ out, int N) {
    __shared__ int s_lds[4][32];
    __shared__ float w_lds[4][32 * 8];
    int wave = threadIdx.x >> 6, lane = threadIdx.x & 63;
    int n = blockIdx.x * 4 + wave;
    if (n >= N) return;
    int hf = blockIdx.y;
    int coff = hf * 128 + lane * 2;
    int start = rowptr[n], end = rowptr[n + 1];
    int hW = (hf << 3) + (lane & 7);   // head this lane computes logits for
    int eW = lane >> 3;                // edge sub-slot 0..7
    float aldW = ald[n * 16 + hW];
    float2 acc = {0.f, 0.f};
    float swp = 0.f;                   // partial w-sum for head hW
    const float* Hh = H + coff;
    for (int base = start; base < end; base += 32) {
        int len = min(32, end - base);
        if (lane < 32) s_lds[wave][lane] = (lane < len) ? col[base + lane] : 0;
        LDS_FENCE();
#pragma unroll
        for (int k = 0; k < 4; ++k) {
            int esub = (k << 3) + eW;
            float w = 0.f;
            if (esub < len) {
                int s = s_lds[wave][esub];
                float v = als[s * 16 + hW] + aldW;
                v = v >= 0.f ? v : NEG_SLOPE * v;
                w = __expf(v);
            }
            w_lds[wave][(esub << 3) + (lane & 7)] = w;  // = k*64+lane: linear
            swp += w;
        }
        LDS_FENCE();
#pragma unroll 4
        for (int e = 0; e < len; ++e) {
            int se = s_lds[wave][e];
            float we = w_lds[wave][(e << 3) + (lane >> 3)];  // broadcast per 8 lanes
            float2 hv = *(const float2*)(Hh + (size_t)se * 256);
            acc.x = fmaf(we, hv.x, acc.x);
            acc.y = fmaf(we, hv.y, acc.y);
        }
        LDS_FENCE();
    }
    swp += __shfl_xor(swp, 8);
    swp += __shfl_xor(swp, 16);
    swp += __shfl_xor(swp, 32);
    float inv = 1.0f / __shfl(swp, lane >> 3);
    float2 b2v = *(const float2*)(bias + coff);
    float2 r;
    r.x = fmaxf(fmaf(acc.x, inv, b2v.x), 0.f);
    r.y = fmaxf(fmaf(acc.y, inv, b2v.y), 0.f);
    *(float2*)(out + (size_t)n * 256 + coff) = r;
}

// ---------- fused mean-pool + final linear: one block per graph ----------
__device__ __forceinline__ int lower_bound_i(const int* __restrict__ a, int n, int v) {
    int lo = 0, hi = n;
    while (lo < hi) {
        int mid = (lo + hi) >> 1;
        if (a[mid] < v) lo = mid + 1; else hi = mid;
    }
    return lo;
}

__global__ __launch_bounds__(1024) void k_pool_final(const float* __restrict__ B,
                                                     const int* __restrict__ batch,
                                                     const float* __restrict__ lw,
                                                     const float* __restrict__ lb,
                                                     float* __restrict__ out,
                                                     int N, int L) {
    __shared__ float psum[4][256];
    __shared__ float csum[256];
    int t = threadIdx.x;
    int c = t & 255, q = t >> 8;
    int g = blockIdx.x;
    int lo = lower_bound_i(batch, N, g);
    int hi = lower_bound_i(batch, N, g + 1);
    int len = hi - lo;
    int per = (len + 3) >> 2;
    int s0 = lo + q * per, s1 = min(hi, s0 + per);
    float acc = 0.f;
    for (int r = s0; r < s1; ++r) acc += B[(size_t)r * 256 + c];
    psum[q][c] = acc;
    __syncthreads();
    if (t < 256) csum[t] = psum[0][t] + psum[1][t] + psum[2][t] + psum[3][t];
    __syncthreads();
    int wave = t >> 6, lane = t & 63;
    if (wave < L) {
        int l = wave;
        float a = csum[lane] * lw[lane * L + l] +
                  csum[lane + 64] * lw[(lane + 64) * L + l] +
                  csum[lane + 128] * lw[(lane + 128) * L + l] +
                  csum[lane + 192] * lw[(lane + 192) * L + l];
#pragma unroll
        for (int off = 32; off >= 1; off >>= 1) a += __shfl_xor(a, off);
        if (lane == 0) out[g * L + l] = a / fmaxf((float)len, 1.0f) + lb[l];
    }
}

extern "C" void kernel_launch(void* const* d_in, const int* in_sizes, int n_in,
                              void* d_out, int out_size, void* d_ws, size_t ws_size,
                              hipStream_t stream) {
    const float* x   = (const float*)d_in[0];
    const int*   ei  = (const int*)d_in[1];
    const int*   bat = (const int*)d_in[2];
    const float* W1  = (const float*)d_in[3];
    const float* as1 = (const float*)d_in[4];
    const float* ad1 = (const float*)d_in[5];
    const float* b1  = (const float*)d_in[6];
    const float* W2  = (const float*)d_in[7];
    const float* as2 = (const float*)d_in[8];
    const float* ad2 = (const float*)d_in[9];
    const float* b2  = (const float*)d_in[10];
    const float* lw  = (const float*)d_in[11];
    const float* lb  = (const float*)d_in[12];
    float* out = (float*)d_out;

    const int N = in_sizes[2];        // 10000
    const int E = in_sizes[1] / 2;    // 320000
    const int G = 64, L = 10;
    const int Etot = E + N;
    const int NP = (N + 31) >> 5;     // partitions of 32 dsts (313)
    const int CE = (Etot + CSR_NB - 1) / CSR_NB;

    // workspace layout
    float* A    = (float*)d_ws;              // [N,256] h1 then h2
    float* B    = A + (size_t)N * 256;       // [N,256] out1 then out2
    float* als1 = B + (size_t)N * 256;       // [N,16]
    float* ald1 = als1 + (size_t)N * 16;
    float* als2 = ald1 + (size_t)N * 16;     // [N]
    float* ald2 = als2 + N;
    int* rowptr   = (int*)(ald2 + N);        // [N+1]
    int* col      = rowptr + N + 1;          // [Etot]
    int* tmp      = col + Etot;              // [Etot] packed (src<<5)|d5
    int* hist     = tmp + Etot;              // [CSR_NB*NP]
    int* partBase = hist + CSR_NB * NP;      // [NP+1]

    const int BS = 256;
    auto nb = [](int n, int b) { return (n + b - 1) / b; };
    int nodes4 = nb(N, 4);
    int rows32 = nb(N, 32);

    // ---- CSR build: partition sort, no global returning atomics ----
    k_parthist<<<CSR_NB, BS, 0, stream>>>(ei, E, N, NP, CE, hist);
    k_partscan<<<1, 512, 0, stream>>>(hist, NP, partBase, rowptr, N);
    k_partscatter<<<CSR_NB, BS, 0, stream>>>(ei, E, N, NP, CE, hist, tmp);
    k_csr_final<<<NP, BS, 0, stream>>>(tmp, partBase, rowptr, col, N);

    // ---- layer 1 ----
    k_gemm_cs<128><<<dim3(rows32, 2), BS, 0, stream>>>(x, W1, A, N);
    k_logits1<<<nb(N * 16, BS), BS, 0, stream>>>(A, as1, ad1, als1, ald1, N * 16);
    k_gather_h16<<<dim3(nodes4, 2), BS, 0, stream>>>(rowptr, col, A, als1, ald1, b1, B, N);

    // ---- layer 2 ----
    k_gemm_cs<256><<<dim3(rows32, 2), BS, 0, stream>>>(B, W2, A, N);
    k_logits2<<<nodes4, BS, 0, stream>>>(A, as2, ad2, als2, ald2, N);
    k_gather_h1<<<dim3(nodes4, 2), BS, 0, stream>>>(rowptr, col, A, als2, ald2, b2, B, N);

    // ---- fused pool + final linear ----
    k_pool_final<<<G, 1024, 0, stream>>>(B, bat, lw, lb, out, N, L);
}